// Round 6
// baseline (946.579 us; speedup 1.0000x reference)
//
#include <hip/hip_runtime.h>
#include <hip/hip_bf16.h>
#include <stdint.h>

#define NN 50000
#define NE 800000
#define HH 128

typedef __bf16 bf16x8 __attribute__((ext_vector_type(8)));
typedef float  f32x4  __attribute__((ext_vector_type(4)));

__device__ __forceinline__ unsigned short f2bf(float f) {
  union { float f; uint32_t u; } v; v.f = f;
  uint32_t r = v.u + 0x7FFFu + ((v.u >> 16) & 1u);
  return (unsigned short)(r >> 16);
}
#if __has_builtin(__builtin_amdgcn_cvt_pk_bf16_f32)
typedef __bf16 bf16x2 __attribute__((ext_vector_type(2)));
__device__ __forceinline__ uint32_t pack2bf(float a, float b) {
  union { bf16x2 v; uint32_t u; } t;
  t.v = __builtin_amdgcn_cvt_pk_bf16_f32(a, b);
  return t.u;
}
#else
__device__ __forceinline__ uint32_t pack2bf(float a, float b) {
  return (uint32_t)f2bf(a) | ((uint32_t)f2bf(b) << 16);
}
#endif
// fast silu/sigmoid: v_rcp instead of IEEE division sequence (bf16 output, 1ulp fine)
__device__ __forceinline__ float silu_f(float x) {
  return x * __builtin_amdgcn_rcpf(1.f + __expf(-x));
}
__device__ __forceinline__ float sigm_f(float x) {
  return __builtin_amdgcn_rcpf(1.f + __expf(-x));
}

// LDS tile blocks: [rows][32 k] bf16, 16B chunk c stored at c ^ ((row>>1)&3)
__device__ __forceinline__ bf16x8 frag_ld(const short* blk, int row, int q) {
  int c = q ^ ((row >> 1) & 3);
  return *(const bf16x8*)(blk + row * 32 + c * 8);
}
// direct global fragment load from pre-swizzled weight layout
__device__ __forceinline__ int wfrag_off(int row, int q) {
  return row * 32 + ((q ^ ((row >> 1) & 3)) * 8);
}

// ---------------- weight prep: transpose to [kk][n][32k] swizzled bf16 ----------------
__global__ void k_prep_weights(const float* We1, const float* We2, const float* Wn1,
                               const float* Wn2, const float* cW1, const float* cW2,
                               short* W1sw, short* W2sw, short* Wn1sw, short* Wn2sw,
                               short* cW1sw, short* cW2sw) {
  int idx = blockIdx.x * 256 + threadIdx.x;
  const float* s; short* d; int ks;
  if (idx < 36864)                    { s = We1;           d = W1sw;          ks = 265; }
  else if ((idx -= 36864) < 36864)    { s = We1 + 33920;   d = W1sw + 36864;  ks = 265; }
  else if ((idx -= 36864) < 16384)    { s = We2;           d = W2sw;          ks = 128; }
  else if ((idx -= 16384) < 16384)    { s = We2 + 16384;   d = W2sw + 16384;  ks = 128; }
  else if ((idx -= 16384) < 32768)    { s = Wn1;           d = Wn1sw;         ks = 256; }
  else if ((idx -= 32768) < 32768)    { s = Wn1 + 32768;   d = Wn1sw + 32768; ks = 256; }
  else if ((idx -= 32768) < 16384)    { s = Wn2;           d = Wn2sw;         ks = 128; }
  else if ((idx -= 16384) < 16384)    { s = Wn2 + 16384;   d = Wn2sw + 16384; ks = 128; }
  else if ((idx -= 16384) < 36864)    { s = cW1;           d = cW1sw;         ks = 265; }
  else if ((idx -= 36864) < 16384)    { s = cW2;           d = cW2sw;         ks = 128; }
  else return;
  int kk = idx >> 12;
  int rem = idx & 4095;
  int n = rem >> 5, kw = rem & 31;
  int cp = kw >> 3, j = kw & 7;
  int c = cp ^ ((n >> 1) & 3);
  int k = kk * 32 + c * 8 + j;
  float v = (k < ks) ? s[k * 128 + n] : 0.f;
  d[idx] = (short)f2bf(v);
}

// ---------------- small prep kernels ----------------
__global__ void k_init_xb(const float* __restrict__ x, short* __restrict__ Anode) {
  int i = blockIdx.x * 256 + threadIdx.x;
  if (i < NN * HH) Anode[(i >> 7) * 256 + (i & 127)] = (short)f2bf(x[i]);
}
__global__ void k_nodeprep(const float* __restrict__ agg, short* __restrict__ Anode) {
  int i = blockIdx.x * 256 + threadIdx.x;
  if (i < NN * HH) Anode[(i >> 7) * 256 + 128 + (i & 127)] = (short)f2bf(agg[i] * 0.01f);
}
__global__ void k_edge_pre(const float* __restrict__ pos, const float* __restrict__ eattr,
                           const int* __restrict__ ei, short* __restrict__ eaPad,
                           float* __restrict__ nd) {
  int e = blockIdx.x * 256 + threadIdx.x;
  if (e >= NE) return;
  int r = ei[e], c = ei[NE + e];
  float dx = pos[r * 3 + 0] - pos[c * 3 + 0];
  float dy = pos[r * 3 + 1] - pos[c * 3 + 1];
  float dz = pos[r * 3 + 2] - pos[c * 3 + 2];
  float d2 = dx * dx + dy * dy + dz * dz;
  float inv = __builtin_amdgcn_rcpf(sqrtf(d2) + 1.f);   // NC = 1.0
  nd[e * 3 + 0] = dx * inv;
  nd[e * 3 + 1] = dy * inv;
  nd[e * 3 + 2] = dz * inv;
  union { unsigned short s[32]; uint4 v[4]; } buf;
  buf.s[0] = f2bf(d2);
#pragma unroll
  for (int j = 0; j < 8; ++j) buf.s[1 + j] = f2bf(eattr[e * 8 + j]);
#pragma unroll
  for (int j = 9; j < 32; ++j) buf.s[j] = 0;
  uint4* dst = (uint4*)(eaPad + (size_t)e * 32);
#pragma unroll
  for (int j = 0; j < 4; ++j) dst[j] = buf.v[j];
}
__global__ void k_pos_final(const float* __restrict__ pos, const float* __restrict__ mask,
                            const float* __restrict__ pagg, float* __restrict__ out) {
  int i = blockIdx.x * 256 + threadIdx.x;
  if (i < NN * 3) out[i] = pos[i] + pagg[i] * 0.01f * mask[i / 3];
}

// ---------------- CSR sort of edges by destination row ----------------
__global__ void k_hist(const int* __restrict__ ei, int* __restrict__ cnt) {
  int e = blockIdx.x * 256 + threadIdx.x;
  if (e < NE) atomicAdd(&cnt[ei[e]], 1);
}
__global__ void k_scan_block(const int* __restrict__ cnt, int* __restrict__ offs,
                             int* __restrict__ bsum) {
  __shared__ int s[256];
  int i = blockIdx.x * 256 + threadIdx.x;
  int v = (i < NN) ? cnt[i] : 0;
  s[threadIdx.x] = v;
  __syncthreads();
#pragma unroll
  for (int d = 1; d < 256; d <<= 1) {
    int t = (threadIdx.x >= d) ? s[threadIdx.x - d] : 0;
    __syncthreads();
    s[threadIdx.x] += t;
    __syncthreads();
  }
  if (i < NN) offs[i] = s[threadIdx.x] - v;
  if (threadIdx.x == 255) bsum[blockIdx.x] = s[255];
}
__global__ void k_scan_top(int* __restrict__ bsum) {
  __shared__ int s[256];
  int v = (threadIdx.x < 196) ? bsum[threadIdx.x] : 0;
  s[threadIdx.x] = v;
  __syncthreads();
#pragma unroll
  for (int d = 1; d < 256; d <<= 1) {
    int t = (threadIdx.x >= d) ? s[threadIdx.x - d] : 0;
    __syncthreads();
    s[threadIdx.x] += t;
    __syncthreads();
  }
  if (threadIdx.x < 196) bsum[threadIdx.x] = s[threadIdx.x] - v;
}
__global__ void k_scan_add(int* __restrict__ offs, const int* __restrict__ bsum) {
  int i = blockIdx.x * 256 + threadIdx.x;
  if (i < NN) offs[i] += bsum[blockIdx.x];
}
__global__ void k_scatter(const int* __restrict__ ei, int* __restrict__ offs,
                          int* __restrict__ perm) {
  int e = blockIdx.x * 256 + threadIdx.x;
  if (e < NE) {
    int p = atomicAdd(&offs[ei[e]], 1);
    perm[p] = e;
  }
}

// ---------------- fused edge/coord MLP GEMM (edges presorted by row) ----------------
// Barrier-free K-loops: MFMA fragments loaded DIRECTLY global->VGPR per lane
// (B-operand lane=edge wants 16B of one edge's features = natural gather;
//  A-operand weight frags are L2-hot). Only the h1 LDS round-trip syncs.
// TRANSPOSED MFMA: A=W-frag, B=he-frag => D[chan][edge] (lane=edge).
template <int COORD>
__global__ __launch_bounds__(256, 4) void k_edge_gemm(
    const short* __restrict__ Anode, const short* __restrict__ eaPad,
    const int* __restrict__ ei, const int* __restrict__ perm,
    const short* __restrict__ W1l, const short* __restrict__ W2l,
    const float* __restrict__ b1, const float* __restrict__ b2,
    const float* __restrict__ wred, const float* __restrict__ batt,
    const float* __restrict__ nd, float* outAcc) {
  __shared__ __align__(16) short A2s[8192];  // h1^T 4x[64e][32c]; then M 2x[128c][32e]
  __shared__ float redp[64][2];
  __shared__ float redv[64];
  __shared__ int srow[64];
  __shared__ int scol[64];
  __shared__ int eorg[64];
  __shared__ __align__(8) unsigned char srunS[64];
  __shared__ int runrowS[64];
  __shared__ int cntS[1];

  const int tid = threadIdx.x;
  const int lane = tid & 63;
  const int w = tid >> 6;
  const int ln = lane & 15, q = lane >> 4;
  const int wm = w >> 1, wn = w & 1;
  const int tile = blockIdx.x;

  if (tid < 64) {
    int eo = perm[tile * 64 + tid];
    eorg[tid] = eo;
    srow[tid] = ei[eo];
    scol[tid] = ei[NE + eo];
  }
  __syncthreads();

  // ---- segmented-run scan over sorted rows (wave 0 only) ----
  bool is_start = (tid < 64) && (tid == 0 || srow[tid] != srow[tid - 1]);
  unsigned long long bmask = __ballot(is_start);
  if (tid == 0) cntS[0] = __popcll(bmask);
  if (tid < 64) {
    int run = __popcll(bmask & ((1ull << lane) - 1ull)) + (is_start ? 1 : 0) - 1;
    srunS[tid] = (unsigned char)run;
    if (is_start) runrowS[run] = srow[tid];
  }
  // (published by the epilogue1 barrier; read only after GEMM2)

  // per-lane fragment sources
  const int e0 = wm * 32 + ln, e1 = e0 + 16;
  const size_t rb0 = (size_t)srow[e0] * 256, rb1 = (size_t)srow[e1] * 256;
  const size_t cb0 = (size_t)scol[e0] * 256, cb1 = (size_t)scol[e1] * 256;
  const size_t ab0 = (size_t)eorg[e0] * 32,  ab1 = (size_t)eorg[e1] * 32;
  int wofs[4];
#pragma unroll
  for (int i = 0; i < 4; ++i) wofs[i] = wfrag_off(wn * 64 + i * 16 + ln, q);

  f32x4 acc[4][2];                           // [chan-tile ni][edge-tile mi]
  const f32x4 zero4 = {0.f, 0.f, 0.f, 0.f};
#pragma unroll
  for (int ni = 0; ni < 4; ++ni)
#pragma unroll
    for (int mi = 0; mi < 2; ++mi) acc[ni][mi] = zero4;

  // -------- GEMM1: h1^T[128c x 64e] = W1^T(A) x he^T(B), barrier-free --------
#pragma unroll
  for (int kk = 0; kk < 9; ++kk) {
    bf16x8 wf[4], hf[2];
#pragma unroll
    for (int i = 0; i < 4; ++i) wf[i] = *(const bf16x8*)(W1l + kk * 4096 + wofs[i]);
    const short *pa0, *pa1;
    if (kk < 4)      { pa0 = Anode + rb0 + kk * 32;       pa1 = Anode + rb1 + kk * 32; }
    else if (kk < 8) { pa0 = Anode + cb0 + (kk - 4) * 32; pa1 = Anode + cb1 + (kk - 4) * 32; }
    else             { pa0 = eaPad + ab0;                 pa1 = eaPad + ab1; }
    hf[0] = *(const bf16x8*)(pa0 + q * 8);
    hf[1] = *(const bf16x8*)(pa1 + q * 8);
#pragma unroll
    for (int ni = 0; ni < 4; ++ni)
#pragma unroll
      for (int mi = 0; mi < 2; ++mi)
        acc[ni][mi] = __builtin_amdgcn_mfma_f32_16x16x32_bf16(wf[ni], hf[mi], acc[ni][mi], 0, 0, 0);
  }

  // -------- epilogue1: silu(h1+b1) -> A2s [edge][chan] via packed b64 writes --------
  float4 b1v[4];
#pragma unroll
  for (int ni = 0; ni < 4; ++ni)
    b1v[ni] = *(const float4*)(b1 + wn * 64 + ni * 16 + q * 4);
#pragma unroll
  for (int ni = 0; ni < 4; ++ni) {
    int cb = wn * 64 + ni * 16 + q * 4;            // 4 consecutive chans per lane
    int kkb = cb >> 5, cc = (cb >> 3) & 3, j0 = cb & 7;
#pragma unroll
    for (int mi = 0; mi < 2; ++mi) {
      int edge = wm * 32 + mi * 16 + ln;
      int addr = kkb * 2048 + edge * 32 + ((cc ^ ((edge >> 1) & 3)) * 8) + j0;
      uint2 pk;
      pk.x = pack2bf(silu_f(acc[ni][mi][0] + b1v[ni].x), silu_f(acc[ni][mi][1] + b1v[ni].y));
      pk.y = pack2bf(silu_f(acc[ni][mi][2] + b1v[ni].z), silu_f(acc[ni][mi][3] + b1v[ni].w));
      *(uint2*)(A2s + addr) = pk;
    }
  }
  __syncthreads();

  // -------- GEMM2: M^T[128c2 x 64e] = W2^T(A) x h1^T(B), barrier-free --------
  f32x4 acc2[4][2];
#pragma unroll
  for (int ni = 0; ni < 4; ++ni)
#pragma unroll
    for (int mi = 0; mi < 2; ++mi) acc2[ni][mi] = zero4;
#pragma unroll
  for (int kk = 0; kk < 4; ++kk) {
    bf16x8 wf[4], hf[2];
#pragma unroll
    for (int i = 0; i < 4; ++i) wf[i] = *(const bf16x8*)(W2l + kk * 4096 + wofs[i]);
#pragma unroll
    for (int i = 0; i < 2; ++i) hf[i] = frag_ld(A2s + kk * 2048, wm * 32 + i * 16 + ln, q);
#pragma unroll
    for (int ni = 0; ni < 4; ++ni)
#pragma unroll
      for (int mi = 0; mi < 2; ++mi)
        acc2[ni][mi] = __builtin_amdgcn_mfma_f32_16x16x32_bf16(wf[ni], hf[mi], acc2[ni][mi], 0, 0, 0);
  }

  // -------- epilogue2: silu + attention/phi dot (mostly in-lane) --------
  float4 b2v[4], wv[4];
#pragma unroll
  for (int ni = 0; ni < 4; ++ni) {
    b2v[ni] = *(const float4*)(b2 + wn * 64 + ni * 16 + q * 4);
    wv[ni]  = *(const float4*)(wred + wn * 64 + ni * 16 + q * 4);
  }
  float p[2] = {0.f, 0.f};
#pragma unroll
  for (int ni = 0; ni < 4; ++ni)
#pragma unroll
    for (int mi = 0; mi < 2; ++mi)
#pragma unroll
      for (int r = 0; r < 4; ++r) {
        float v = silu_f(acc2[ni][mi][r] + ((const float*)&b2v[ni])[r]);
        acc2[ni][mi][r] = v;
        p[mi] += v * ((const float*)&wv[ni])[r];
      }
#pragma unroll
  for (int mi = 0; mi < 2; ++mi) {
    p[mi] += __shfl_xor(p[mi], 16, 64);
    p[mi] += __shfl_xor(p[mi], 32, 64);
  }
  if (lane < 16) {
#pragma unroll
    for (int mi = 0; mi < 2; ++mi) redp[wm * 32 + mi * 16 + ln][wn] = p[mi];
  }
  __syncthreads();   // redp ready; all waves done with A2s (GEMM2)

  if (COORD == 0) {
    if (tid < 64) redv[tid] = sigm_f(redp[tid][0] + redp[tid][1] + batt[0]);
    __syncthreads();
    // M-tile 2x[128 chan][32 edge] swizzled blocks (B-operand layout for S-GEMM)
    float attv[2] = {redv[wm * 32 + ln], redv[wm * 32 + 16 + ln]};
#pragma unroll
    for (int ni = 0; ni < 4; ++ni)
#pragma unroll
      for (int mi = 0; mi < 2; ++mi) {
        int eb = mi * 16 + ln;
        int cE = (eb >> 3) & 3, jE = eb & 7;
#pragma unroll
        for (int r = 0; r < 4; ++r) {
          int chan2 = wn * 64 + ni * 16 + q * 4 + r;
          int addr = wm * 4096 + chan2 * 32 + ((cE ^ ((chan2 >> 1) & 3)) * 8) + jE;
          union { float f; uint32_t u; } vv;
          vv.f = acc2[ni][mi][r] * attv[mi];
          A2s[addr] = (short)((vv.u + 0x8000u) >> 16);   // round-half-up to bf16
        }
      }
    __syncthreads();
    // segment-sum via MFMA: agg[run][chan] = S[run][edge] @ M[edge][chan]
    const int nruns = cntS[0];
    bf16x8 bfrg[2][2];
#pragma unroll
    for (int kk = 0; kk < 2; ++kk)
#pragma unroll
      for (int ni = 0; ni < 2; ++ni)
        bfrg[kk][ni] = frag_ld(A2s + kk * 4096, w * 32 + ni * 16 + ln, q);
    const int npass = (nruns + 15) >> 4;
    for (int pp = 0; pp < npass; ++pp) {
      const unsigned int base = pp * 16;
      f32x4 a3c[2] = {zero4, zero4};
#pragma unroll
      for (int kk = 0; kk < 2; ++kk) {
        uint2 sb = *(const uint2*)(srunS + kk * 32 + q * 8);
        union { short s[8]; bf16x8 v; } af;
#pragma unroll
        for (int j = 0; j < 4; ++j)
          af.s[j] = (((sb.x >> (8 * j)) & 255u) == base + (unsigned)ln) ? (short)0x3F80 : (short)0;
#pragma unroll
        for (int j = 0; j < 4; ++j)
          af.s[4 + j] = (((sb.y >> (8 * j)) & 255u) == base + (unsigned)ln) ? (short)0x3F80 : (short)0;
        a3c[0] = __builtin_amdgcn_mfma_f32_16x16x32_bf16(af.v, bfrg[kk][0], a3c[0], 0, 0, 0);
        a3c[1] = __builtin_amdgcn_mfma_f32_16x16x32_bf16(af.v, bfrg[kk][1], a3c[1], 0, 0, 0);
      }
#pragma unroll
      for (int ni = 0; ni < 2; ++ni)
#pragma unroll
        for (int r = 0; r < 4; ++r) {
          int run = (int)base + q * 4 + r;
          if (run < nruns) {
            int rw = runrowS[run];
            atomicAdd(&outAcc[(size_t)rw * 128 + (w * 32 + ni * 16 + ln)], a3c[ni][r]);
          }
        }
    }
  } else {
    float* ndl = (float*)A2s;   // reuse: [64][3]
    if (tid < 64) {
      int eo = eorg[tid];
      float phi = redp[tid][0] + redp[tid][1];
      ndl[tid * 3 + 0] = nd[eo * 3 + 0] * phi;
      ndl[tid * 3 + 1] = nd[eo * 3 + 1] * phi;
      ndl[tid * 3 + 2] = nd[eo * 3 + 2] * phi;
    }
    __syncthreads();
    if (is_start) {   // run-start walkers (tid<64 implied)
      int myrow = srow[tid];
      float s0 = 0.f, s1 = 0.f, s2 = 0.f;
      for (int j = tid; j < 64 && srow[j] == myrow; ++j) {
        s0 += ndl[j * 3 + 0];
        s1 += ndl[j * 3 + 1];
        s2 += ndl[j * 3 + 2];
      }
      atomicAdd(&outAcc[myrow * 3 + 0], s0);
      atomicAdd(&outAcc[myrow * 3 + 1], s1);
      atomicAdd(&outAcc[myrow * 3 + 2], s2);
    }
  }
}

// ---------------- node MLP GEMM (residual update, 128-node tiles) ----------------
// Same barrier-free direct-fragment-load structure.
__global__ __launch_bounds__(256) void k_node_gemm(
    short* Anode, const short* __restrict__ Wn1l, const short* __restrict__ Wn2l,
    const float* __restrict__ b1, const float* __restrict__ b2,
    const float* __restrict__ xres, float* __restrict__ xout) {
  __shared__ short A2s[4 * 4096];

  const int tid = threadIdx.x;
  const int lane = tid & 63;
  const int w = tid >> 6;
  const int ln = lane & 15, q = lane >> 4;
  const int wm = w >> 1, wn = w & 1;
  const int tile = blockIdx.x;

  size_t nbase[4];
  int wofs[4];
#pragma unroll
  for (int i = 0; i < 4; ++i) {
    int node = tile * 128 + wm * 64 + i * 16 + ln;
    nbase[i] = (size_t)(node < NN ? node : (NN - 1)) * 256;
    wofs[i] = wfrag_off(wn * 64 + i * 16 + ln, q);
  }

  f32x4 acc[4][4];
  const f32x4 zero4 = {0.f, 0.f, 0.f, 0.f};
#pragma unroll
  for (int mi = 0; mi < 4; ++mi)
#pragma unroll
    for (int ni = 0; ni < 4; ++ni) acc[mi][ni] = zero4;

#pragma unroll
  for (int kk = 0; kk < 8; ++kk) {
    bf16x8 af[4], bfr[4];
#pragma unroll
    for (int i = 0; i < 4; ++i) af[i] = *(const bf16x8*)(Anode + nbase[i] + kk * 32 + q * 8);
#pragma unroll
    for (int i = 0; i < 4; ++i) bfr[i] = *(const bf16x8*)(Wn1l + kk * 4096 + wofs[i]);
#pragma unroll
    for (int mi = 0; mi < 4; ++mi)
#pragma unroll
      for (int ni = 0; ni < 4; ++ni)
        acc[mi][ni] = __builtin_amdgcn_mfma_f32_16x16x32_bf16(af[mi], bfr[ni], acc[mi][ni], 0, 0, 0);
  }

  float b1v[4];
#pragma unroll
  for (int ni = 0; ni < 4; ++ni) b1v[ni] = b1[wn * 64 + ni * 16 + ln];
#pragma unroll
  for (int mi = 0; mi < 4; ++mi)
#pragma unroll
    for (int ni = 0; ni < 4; ++ni) {
      int chan = wn * 64 + ni * 16 + ln;
      int kkb = chan >> 5, c = (chan >> 3) & 3, jj = chan & 7;
#pragma unroll
      for (int r = 0; r < 4; ++r) {
        int m = wm * 64 + mi * 16 + q * 4 + r;
        float v = silu_f(acc[mi][ni][r] + b1v[ni]);
        A2s[kkb * 4096 + m * 32 + ((c ^ ((m >> 1) & 3)) * 8) + jj] = (short)f2bf(v);
      }
    }
  __syncthreads();

  f32x4 acc2[4][4];
#pragma unroll
  for (int mi = 0; mi < 4; ++mi)
#pragma unroll
    for (int ni = 0; ni < 4; ++ni) acc2[mi][ni] = zero4;
#pragma unroll
  for (int kk = 0; kk < 4; ++kk) {
    bf16x8 af[4], bfr[4];
#pragma unroll
    for (int i = 0; i < 4; ++i) af[i] = frag_ld(A2s + kk * 4096, wm * 64 + i * 16 + ln, q);
#pragma unroll
    for (int i = 0; i < 4; ++i) bfr[i] = *(const bf16x8*)(Wn2l + kk * 4096 + wofs[i]);
#pragma unroll
    for (int mi = 0; mi < 4; ++mi)
#pragma unroll
      for (int ni = 0; ni < 4; ++ni)
        acc2[mi][ni] = __builtin_amdgcn_mfma_f32_16x16x32_bf16(af[mi], bfr[ni], acc2[mi][ni], 0, 0, 0);
  }

  float b2v[4];
#pragma unroll
  for (int ni = 0; ni < 4; ++ni) b2v[ni] = b2[wn * 64 + ni * 16 + ln];
#pragma unroll
  for (int mi = 0; mi < 4; ++mi)
#pragma unroll
    for (int r = 0; r < 4; ++r) {
      int m = wm * 64 + mi * 16 + q * 4 + r;
      int node = tile * 128 + m;
      if (node < NN) {
#pragma unroll
        for (int ni = 0; ni < 4; ++ni) {
          int chan = wn * 64 + ni * 16 + ln;
          float v = acc2[mi][ni][r] + b2v[ni] + xres[(size_t)node * 128 + chan];
          xout[(size_t)node * 128 + chan] = v;
          Anode[(size_t)node * 256 + chan] = (short)f2bf(v);
        }
      }
    }
}

extern "C" void kernel_launch(void* const* d_in, const int* in_sizes, int n_in,
                              void* d_out, int out_size, void* d_ws, size_t ws_size,
                              hipStream_t stream) {
  const float* x    = (const float*)d_in[0];
  const float* pos  = (const float*)d_in[1];
  const float* mask = (const float*)d_in[2];
  const float* eattr= (const float*)d_in[3];
  const int*   ei   = (const int*)d_in[4];
  const float* We1  = (const float*)d_in[5];
  const float* be1  = (const float*)d_in[6];
  const float* We2  = (const float*)d_in[7];
  const float* be2  = (const float*)d_in[8];
  const float* Watt = (const float*)d_in[9];
  const float* batt = (const float*)d_in[10];
  const float* Wn1  = (const float*)d_in[11];
  const float* bn1  = (const float*)d_in[12];
  const float* Wn2  = (const float*)d_in[13];
  const float* bn2  = (const float*)d_in[14];
  const float* cW1  = (const float*)d_in[15];
  const float* cb1  = (const float*)d_in[16];
  const float* cW2  = (const float*)d_in[17];
  const float* cb2  = (const float*)d_in[18];
  const float* cW3  = (const float*)d_in[19];

  char* p = (char*)d_ws;
  auto carve = [&](size_t bytes) { char* r = p; p += (bytes + 511) & ~(size_t)511; return r; };
  short* Anode = (short*)carve((size_t)NN * 256 * 2);
  short* eaPad = (short*)carve((size_t)NE * 32 * 2);
  float* nd    = (float*)carve((size_t)NE * 3 * 4);
  float* agg   = (float*)carve((size_t)NN * 128 * 4);
  float* xcur  = (float*)carve((size_t)NN * 128 * 4);
  float* pagg  = (float*)carve((size_t)NN * 3 * 4);
  short* W1sw  = (short*)carve(2 * 36864 * 2);
  short* W2sw  = (short*)carve(2 * 16384 * 2);
  short* Wn1sw = (short*)carve(2 * 32768 * 2);
  short* Wn2sw = (short*)carve(2 * 16384 * 2);
  short* cW1sw = (short*)carve(36864 * 2);
  short* cW2sw = (short*)carve(16384 * 2);
  int*   cnt   = (int*)carve((size_t)NN * 4);
  int*   offs  = (int*)carve((size_t)NN * 4);
  int*   bsum  = (int*)carve(256 * 4);
  int*   perm  = (int*)carve((size_t)NE * 4);

  float* xout_f = (float*)d_out;        // N*128
  float* pout_f = xout_f + NN * 128;    // N*3

  k_prep_weights<<<1008, 256, 0, stream>>>(We1, We2, Wn1, Wn2, cW1, cW2,
                                           W1sw, W2sw, Wn1sw, Wn2sw, cW1sw, cW2sw);
  k_init_xb<<<25000, 256, 0, stream>>>(x, Anode);
  k_edge_pre<<<3125, 256, 0, stream>>>(pos, eattr, ei, eaPad, nd);

  // build row-sorted edge permutation (CSR order)
  hipMemsetAsync(cnt, 0, (size_t)NN * 4, stream);
  k_hist<<<3125, 256, 0, stream>>>(ei, cnt);
  k_scan_block<<<196, 256, 0, stream>>>(cnt, offs, bsum);
  k_scan_top<<<1, 256, 0, stream>>>(bsum);
  k_scan_add<<<196, 256, 0, stream>>>(offs, bsum);
  k_scatter<<<3125, 256, 0, stream>>>(ei, offs, perm);

  for (int l = 0; l < 2; ++l) {
    hipMemsetAsync(agg, 0, (size_t)NN * 128 * 4, stream);
    k_edge_gemm<0><<<12500, 256, 0, stream>>>(Anode, eaPad, ei, perm,
        W1sw + l * 36864, W2sw + l * 16384, be1 + l * 128, be2 + l * 128,
        Watt + l * 128, batt + l, (const float*)nullptr, agg);
    k_nodeprep<<<25000, 256, 0, stream>>>(agg, Anode);
    k_node_gemm<<<391, 256, 0, stream>>>(Anode,
        Wn1sw + l * 32768, Wn2sw + l * 16384, bn1 + l * 128, bn2 + l * 128,
        l == 0 ? x : xcur, l == 0 ? xcur : xout_f);
  }
  hipMemsetAsync(pagg, 0, (size_t)NN * 3 * 4, stream);
  k_edge_gemm<1><<<12500, 256, 0, stream>>>(Anode, eaPad, ei, perm,
      cW1sw, cW2sw, cb1, cb2, cW3, (const float*)nullptr, nd, pagg);
  k_pos_final<<<587, 256, 0, stream>>>(pos, mask, pagg, pout_f);
}

// Round 7
// 875.686 us; speedup vs baseline: 1.0810x; 1.0810x over previous
//
#include <hip/hip_runtime.h>
#include <hip/hip_bf16.h>
#include <stdint.h>

#define NN 50000
#define NE 800000
#define HH 128

typedef __bf16 bf16x8 __attribute__((ext_vector_type(8)));
typedef float  f32x4  __attribute__((ext_vector_type(4)));
typedef long   f8frag;   // 8 fp8 bytes = i64 MFMA operand

__device__ __forceinline__ unsigned short f2bf(float f) {
  union { float f; uint32_t u; } v; v.f = f;
  uint32_t r = v.u + 0x7FFFu + ((v.u >> 16) & 1u);
  return (unsigned short)(r >> 16);
}
#if __has_builtin(__builtin_amdgcn_cvt_pk_bf16_f32)
typedef __bf16 bf16x2 __attribute__((ext_vector_type(2)));
__device__ __forceinline__ uint32_t pack2bf(float a, float b) {
  union { bf16x2 v; uint32_t u; } t;
  t.v = __builtin_amdgcn_cvt_pk_bf16_f32(a, b);
  return t.u;
}
#else
__device__ __forceinline__ uint32_t pack2bf(float a, float b) {
  return (uint32_t)f2bf(a) | ((uint32_t)f2bf(b) << 16);
}
#endif
__device__ __forceinline__ uint8_t f2fp8(float v) {
  return (uint8_t)(__builtin_amdgcn_cvt_pk_fp8_f32(v, 0.f, 0, false) & 0xff);
}
// fast silu/sigmoid
__device__ __forceinline__ float silu_f(float x) {
  return x * __builtin_amdgcn_rcpf(1.f + __expf(-x));
}
__device__ __forceinline__ float sigm_f(float x) {
  return __builtin_amdgcn_rcpf(1.f + __expf(-x));
}

// LDS tile blocks (bf16): [rows][32 k], 16B chunk c stored at c ^ ((row>>1)&3)
__device__ __forceinline__ bf16x8 frag_ld(const short* blk, int row, int q) {
  int c = q ^ ((row >> 1) & 3);
  return *(const bf16x8*)(blk + row * 32 + c * 8);
}
// bf16 global weight frag offset (swizzled prep layout, short-indexed)
__device__ __forceinline__ int wfrag_off(int row, int q) {
  return row * 32 + ((q ^ ((row >> 1) & 3)) * 8);
}

// ---------------- weight prep ----------------
// W1f8: 3 sets (GCL0, GCL1, coord) x [9 kk][128 n][32 k] fp8 bytes, plain layout
// W2sw: 3 sets bf16 swizzled; Wn1sw/Wn2sw: 2 sets bf16 swizzled
__global__ void k_prep_weights(const float* We1, const float* We2, const float* Wn1,
                               const float* Wn2, const float* cW1, const float* cW2,
                               uint8_t* W1f8, short* W2sw, short* Wn1sw, short* Wn2sw) {
  int idx = blockIdx.x * 256 + threadIdx.x;
  if (idx < 110592) {                      // fp8 W1 (ks=265)
    int l = idx / 36864, rem = idx % 36864;
    const float* s = (l == 0) ? We1 : (l == 1) ? We1 + 33920 : cW1;
    int kkb = rem >> 12, r2 = rem & 4095;
    int n = r2 >> 5, kw = r2 & 31;
    int k = kkb * 32 + kw;
    float v = (k < 265) ? s[k * 128 + n] : 0.f;
    W1f8[idx] = f2fp8(v);
    return;
  }
  idx -= 110592;
  if (idx < 49152) {                       // bf16 W2, 3 sets, ks=128
    int l = idx >> 14, rem = idx & 16383;
    const float* s = (l == 0) ? We2 : (l == 1) ? We2 + 16384 : cW2;
    int kkb = rem >> 12, r2 = rem & 4095, n = r2 >> 5, kw = r2 & 31;
    int cp = kw >> 3, j = kw & 7, c = cp ^ ((n >> 1) & 3);
    int k = kkb * 32 + c * 8 + j;
    W2sw[(l << 14) + (rem)] = (short)f2bf(s[k * 128 + n]);
    return;
  }
  idx -= 49152;
  if (idx < 65536) {                       // bf16 Wn1, 2 sets, ks=256
    int l = idx >> 15, rem = idx & 32767;
    const float* s = Wn1 + l * 32768;
    int kkb = rem >> 12, r2 = rem & 4095, n = r2 >> 5, kw = r2 & 31;
    int cp = kw >> 3, j = kw & 7, c = cp ^ ((n >> 1) & 3);
    int k = kkb * 32 + c * 8 + j;
    Wn1sw[(l << 15) + rem] = (short)f2bf(s[k * 128 + n]);
    return;
  }
  idx -= 65536;
  if (idx < 32768) {                       // bf16 Wn2, 2 sets, ks=128
    int l = idx >> 14, rem = idx & 16383;
    const float* s = Wn2 + l * 16384;
    int kkb = rem >> 12, r2 = rem & 4095, n = r2 >> 5, kw = r2 & 31;
    int cp = kw >> 3, j = kw & 7, c = cp ^ ((n >> 1) & 3);
    int k = kkb * 32 + c * 8 + j;
    Wn2sw[(l << 14) + rem] = (short)f2bf(s[k * 128 + n]);
  }
}

// ---------------- small prep kernels ----------------
__global__ void k_init_xb(const float* __restrict__ x, short* __restrict__ Anode) {
  int i = blockIdx.x * 256 + threadIdx.x;
  if (i < NN * HH) Anode[(i >> 7) * 256 + (i & 127)] = (short)f2bf(x[i]);
}
__global__ void k_xf8(const float* __restrict__ src, uint8_t* __restrict__ XF8) {
  int i = blockIdx.x * 256 + threadIdx.x;
  if (i < NN * 32) {
    float4 v = ((const float4*)src)[i];
    int r = __builtin_amdgcn_cvt_pk_fp8_f32(v.x, v.y, 0, false);
    r = __builtin_amdgcn_cvt_pk_fp8_f32(v.z, v.w, r, true);
    ((uint32_t*)XF8)[i] = (uint32_t)r;
  }
}
__global__ void k_nodeprep(const float* __restrict__ agg, short* __restrict__ Anode) {
  int i = blockIdx.x * 256 + threadIdx.x;
  if (i < NN * HH) Anode[(i >> 7) * 256 + 128 + (i & 127)] = (short)f2bf(agg[i] * 0.01f);
}
// after sort: original-order streaming reads, scatter-writes into sorted slots
__global__ void k_edge_pre(const float* __restrict__ pos, const float* __restrict__ eattr,
                           const int* __restrict__ ei, const int* __restrict__ inv,
                           int* __restrict__ rowS, int* __restrict__ colS,
                           uint8_t* __restrict__ eaF8, float* __restrict__ ndS) {
  int e = blockIdx.x * 256 + threadIdx.x;
  if (e >= NE) return;
  int r = ei[e], c = ei[NE + e];
  float dx = pos[r * 3 + 0] - pos[c * 3 + 0];
  float dy = pos[r * 3 + 1] - pos[c * 3 + 1];
  float dz = pos[r * 3 + 2] - pos[c * 3 + 2];
  float d2 = dx * dx + dy * dy + dz * dz;
  float invd = __builtin_amdgcn_rcpf(sqrtf(d2) + 1.f);   // NC = 1.0
  int p = inv[e];
  rowS[p] = r;
  colS[p] = c;
  ndS[p * 3 + 0] = dx * invd;
  ndS[p * 3 + 1] = dy * invd;
  ndS[p * 3 + 2] = dz * invd;
  const float* ea = eattr + (size_t)e * 8;
  uint32_t w0 = __builtin_amdgcn_cvt_pk_fp8_f32(d2, ea[0], 0, false);
  w0 = __builtin_amdgcn_cvt_pk_fp8_f32(ea[1], ea[2], w0, true);
  uint32_t w1 = __builtin_amdgcn_cvt_pk_fp8_f32(ea[3], ea[4], 0, false);
  w1 = __builtin_amdgcn_cvt_pk_fp8_f32(ea[5], ea[6], w1, true);
  uint32_t w2 = __builtin_amdgcn_cvt_pk_fp8_f32(ea[7], 0.f, 0, false);
  uint4 v = {w0, w1, w2, 0u};
  *(uint4*)(eaF8 + (size_t)p * 16) = v;
}
__global__ void k_pos_final(const float* __restrict__ pos, const float* __restrict__ mask,
                            const float* __restrict__ pagg, float* __restrict__ out) {
  int i = blockIdx.x * 256 + threadIdx.x;
  if (i < NN * 3) out[i] = pos[i] + pagg[i] * 0.01f * mask[i / 3];
}

// ---------------- CSR sort of edges by destination row ----------------
__global__ void k_hist(const int* __restrict__ ei, int* __restrict__ cnt) {
  int e = blockIdx.x * 256 + threadIdx.x;
  if (e < NE) atomicAdd(&cnt[ei[e]], 1);
}
__global__ void k_scan_block(const int* __restrict__ cnt, int* __restrict__ offs,
                             int* __restrict__ bsum) {
  __shared__ int s[256];
  int i = blockIdx.x * 256 + threadIdx.x;
  int v = (i < NN) ? cnt[i] : 0;
  s[threadIdx.x] = v;
  __syncthreads();
#pragma unroll
  for (int d = 1; d < 256; d <<= 1) {
    int t = (threadIdx.x >= d) ? s[threadIdx.x - d] : 0;
    __syncthreads();
    s[threadIdx.x] += t;
    __syncthreads();
  }
  if (i < NN) offs[i] = s[threadIdx.x] - v;
  if (threadIdx.x == 255) bsum[blockIdx.x] = s[255];
}
__global__ void k_scan_top(int* __restrict__ bsum) {
  __shared__ int s[256];
  int v = (threadIdx.x < 196) ? bsum[threadIdx.x] : 0;
  s[threadIdx.x] = v;
  __syncthreads();
#pragma unroll
  for (int d = 1; d < 256; d <<= 1) {
    int t = (threadIdx.x >= d) ? s[threadIdx.x - d] : 0;
    __syncthreads();
    s[threadIdx.x] += t;
    __syncthreads();
  }
  if (threadIdx.x < 196) bsum[threadIdx.x] = s[threadIdx.x] - v;
}
__global__ void k_scan_add(int* __restrict__ offs, const int* __restrict__ bsum) {
  int i = blockIdx.x * 256 + threadIdx.x;
  if (i < NN) offs[i] += bsum[blockIdx.x];
}
__global__ void k_scatter(const int* __restrict__ ei, int* __restrict__ offs,
                          int* __restrict__ inv) {
  int e = blockIdx.x * 256 + threadIdx.x;
  if (e < NE) inv[e] = atomicAdd(&offs[ei[e]], 1);
}

// ---------------- fused edge/coord MLP GEMM (edges presorted by row) ----------------
// GEMM1 in fp8 (gathered XF8/eaF8 + fp8 W1), GEMM2/h1/segment-sum in bf16.
// TRANSPOSED MFMA: A=W-frag, B=he-frag => D[chan][edge] (lane=edge).
template <int COORD>
__global__ __launch_bounds__(256, 4) void k_edge_gemm(
    const uint8_t* __restrict__ XF8, const uint8_t* __restrict__ eaF8,
    const int* __restrict__ rowS, const int* __restrict__ colS,
    const uint8_t* __restrict__ W1f8, const short* __restrict__ W2l,
    const float* __restrict__ b1, const float* __restrict__ b2,
    const float* __restrict__ wred, const float* __restrict__ batt,
    const float* __restrict__ ndS, float* outAcc) {
  __shared__ __align__(16) short A2s[8192];  // h1^T 4x[64e][32c]; then M 2x[128c][32e]
  __shared__ float redp[64][2];
  __shared__ float redv[64];
  __shared__ int srow[64];
  __shared__ __align__(8) unsigned char srunS[64];
  __shared__ int runrowS[64];
  __shared__ int cntS[1];

  const int tid = threadIdx.x;
  const int lane = tid & 63;
  const int w = tid >> 6;
  const int ln = lane & 15, q = lane >> 4;
  const int wm = w >> 1, wn = w & 1;
  const int tile = blockIdx.x;

  if (tid < 64) srow[tid] = rowS[tile * 64 + tid];
  __syncthreads();

  // ---- segmented-run scan over sorted rows (wave 0 only) ----
  bool is_start = (tid < 64) && (tid == 0 || srow[tid] != srow[tid - 1]);
  unsigned long long bmask = __ballot(is_start);
  if (tid == 0) cntS[0] = __popcll(bmask);
  if (tid < 64) {
    int run = __popcll(bmask & ((1ull << lane) - 1ull)) + (is_start ? 1 : 0) - 1;
    srunS[tid] = (unsigned char)run;
    if (is_start) runrowS[run] = srow[tid];
  }
  // (published by epilogue1's barrier; read only after GEMM2)

  // per-lane fragment sources (fp8: 8B per frag)
  const int e0 = wm * 32 + ln, e1 = e0 + 16;
  const size_t rb0 = (size_t)srow[e0] * 128, rb1 = (size_t)srow[e1] * 128;
  const size_t cb0 = (size_t)colS[tile * 64 + e0] * 128;
  const size_t cb1 = (size_t)colS[tile * 64 + e1] * 128;
  const size_t ea0 = (size_t)(tile * 64 + e0) * 16 + (q & 1) * 8;
  const size_t ea1 = (size_t)(tile * 64 + e1) * 16 + (q & 1) * 8;
  int wofs8[4], wofs[4];
#pragma unroll
  for (int i = 0; i < 4; ++i) {
    wofs8[i] = (wn * 64 + i * 16 + ln) * 32 + q * 8;      // fp8 bytes
    wofs[i] = wfrag_off(wn * 64 + i * 16 + ln, q);        // bf16 shorts
  }

  f32x4 acc[4][2];                           // [chan-tile ni][edge-tile mi]
  const f32x4 zero4 = {0.f, 0.f, 0.f, 0.f};
#pragma unroll
  for (int ni = 0; ni < 4; ++ni)
#pragma unroll
    for (int mi = 0; mi < 2; ++mi) acc[ni][mi] = zero4;

  // -------- GEMM1 (fp8): h1^T[128c x 64e] = W1^T(A) x he^T(B), barrier-free --------
#pragma unroll
  for (int kk = 0; kk < 9; ++kk) {
    f8frag wf[4], hf[2];
#pragma unroll
    for (int i = 0; i < 4; ++i) wf[i] = *(const f8frag*)(W1f8 + kk * 4096 + wofs8[i]);
    if (kk < 4) {
      hf[0] = *(const f8frag*)(XF8 + rb0 + kk * 32 + q * 8);
      hf[1] = *(const f8frag*)(XF8 + rb1 + kk * 32 + q * 8);
    } else if (kk < 8) {
      hf[0] = *(const f8frag*)(XF8 + cb0 + (kk - 4) * 32 + q * 8);
      hf[1] = *(const f8frag*)(XF8 + cb1 + (kk - 4) * 32 + q * 8);
    } else {
      hf[0] = (q < 2) ? *(const f8frag*)(eaF8 + ea0) : 0L;
      hf[1] = (q < 2) ? *(const f8frag*)(eaF8 + ea1) : 0L;
    }
#pragma unroll
    for (int ni = 0; ni < 4; ++ni)
#pragma unroll
      for (int mi = 0; mi < 2; ++mi)
        acc[ni][mi] = __builtin_amdgcn_mfma_f32_16x16x32_fp8_fp8(wf[ni], hf[mi], acc[ni][mi], 0, 0, 0);
  }

  // -------- epilogue1: silu(h1+b1) -> A2s bf16 [edge][chan] via packed b64 writes --------
  float4 b1v[4];
#pragma unroll
  for (int ni = 0; ni < 4; ++ni)
    b1v[ni] = *(const float4*)(b1 + wn * 64 + ni * 16 + q * 4);
#pragma unroll
  for (int ni = 0; ni < 4; ++ni) {
    int cb = wn * 64 + ni * 16 + q * 4;            // 4 consecutive chans per lane
    int kkb = cb >> 5, cc = (cb >> 3) & 3, j0 = cb & 7;
#pragma unroll
    for (int mi = 0; mi < 2; ++mi) {
      int edge = wm * 32 + mi * 16 + ln;
      int addr = kkb * 2048 + edge * 32 + ((cc ^ ((edge >> 1) & 3)) * 8) + j0;
      uint2 pk;
      pk.x = pack2bf(silu_f(acc[ni][mi][0] + b1v[ni].x), silu_f(acc[ni][mi][1] + b1v[ni].y));
      pk.y = pack2bf(silu_f(acc[ni][mi][2] + b1v[ni].z), silu_f(acc[ni][mi][3] + b1v[ni].w));
      *(uint2*)(A2s + addr) = pk;
    }
  }
  __syncthreads();

  // -------- GEMM2 (bf16): M^T[128c2 x 64e] = W2^T(A) x h1^T(B), barrier-free --------
  f32x4 acc2[4][2];
#pragma unroll
  for (int ni = 0; ni < 4; ++ni)
#pragma unroll
    for (int mi = 0; mi < 2; ++mi) acc2[ni][mi] = zero4;
#pragma unroll
  for (int kk = 0; kk < 4; ++kk) {
    bf16x8 wf[4], hf[2];
#pragma unroll
    for (int i = 0; i < 4; ++i) wf[i] = *(const bf16x8*)(W2l + kk * 4096 + wofs[i]);
#pragma unroll
    for (int i = 0; i < 2; ++i) hf[i] = frag_ld(A2s + kk * 2048, wm * 32 + i * 16 + ln, q);
#pragma unroll
    for (int ni = 0; ni < 4; ++ni)
#pragma unroll
      for (int mi = 0; mi < 2; ++mi)
        acc2[ni][mi] = __builtin_amdgcn_mfma_f32_16x16x32_bf16(wf[ni], hf[mi], acc2[ni][mi], 0, 0, 0);
  }

  // -------- epilogue2: silu + attention/phi dot (mostly in-lane) --------
  float4 b2v[4], wv[4];
#pragma unroll
  for (int ni = 0; ni < 4; ++ni) {
    b2v[ni] = *(const float4*)(b2 + wn * 64 + ni * 16 + q * 4);
    wv[ni]  = *(const float4*)(wred + wn * 64 + ni * 16 + q * 4);
  }
  float p[2] = {0.f, 0.f};
#pragma unroll
  for (int ni = 0; ni < 4; ++ni)
#pragma unroll
    for (int mi = 0; mi < 2; ++mi)
#pragma unroll
      for (int r = 0; r < 4; ++r) {
        float v = silu_f(acc2[ni][mi][r] + ((const float*)&b2v[ni])[r]);
        acc2[ni][mi][r] = v;
        p[mi] += v * ((const float*)&wv[ni])[r];
      }
#pragma unroll
  for (int mi = 0; mi < 2; ++mi) {
    p[mi] += __shfl_xor(p[mi], 16, 64);
    p[mi] += __shfl_xor(p[mi], 32, 64);
  }
  if (lane < 16) {
#pragma unroll
    for (int mi = 0; mi < 2; ++mi) redp[wm * 32 + mi * 16 + ln][wn] = p[mi];
  }
  __syncthreads();   // redp ready; all waves done with A2s (GEMM2)

  if (COORD == 0) {
    if (tid < 64) redv[tid] = sigm_f(redp[tid][0] + redp[tid][1] + batt[0]);
    __syncthreads();
    // M-tile 2x[128 chan][32 edge] swizzled blocks (B-operand layout for S-GEMM)
    float attv[2] = {redv[wm * 32 + ln], redv[wm * 32 + 16 + ln]};
#pragma unroll
    for (int ni = 0; ni < 4; ++ni)
#pragma unroll
      for (int mi = 0; mi < 2; ++mi) {
        int eb = mi * 16 + ln;
        int cE = (eb >> 3) & 3, jE = eb & 7;
#pragma unroll
        for (int r = 0; r < 4; ++r) {
          int chan2 = wn * 64 + ni * 16 + q * 4 + r;
          int addr = wm * 4096 + chan2 * 32 + ((cE ^ ((chan2 >> 1) & 3)) * 8) + jE;
          union { float f; uint32_t u; } vv;
          vv.f = acc2[ni][mi][r] * attv[mi];
          A2s[addr] = (short)((vv.u + 0x8000u) >> 16);   // round-half-up to bf16
        }
      }
    __syncthreads();
    // segment-sum via MFMA: agg[run][chan] = S[run][edge] @ M[edge][chan]
    const int nruns = cntS[0];
    bf16x8 bfrg[2][2];
#pragma unroll
    for (int kk = 0; kk < 2; ++kk)
#pragma unroll
      for (int ni = 0; ni < 2; ++ni)
        bfrg[kk][ni] = frag_ld(A2s + kk * 4096, w * 32 + ni * 16 + ln, q);
    const int npass = (nruns + 15) >> 4;
    for (int pp = 0; pp < npass; ++pp) {
      const unsigned int base = pp * 16;
      f32x4 a3c[2] = {zero4, zero4};
#pragma unroll
      for (int kk = 0; kk < 2; ++kk) {
        uint2 sb = *(const uint2*)(srunS + kk * 32 + q * 8);
        union { short s[8]; bf16x8 v; } af;
#pragma unroll
        for (int j = 0; j < 4; ++j)
          af.s[j] = (((sb.x >> (8 * j)) & 255u) == base + (unsigned)ln) ? (short)0x3F80 : (short)0;
#pragma unroll
        for (int j = 0; j < 4; ++j)
          af.s[4 + j] = (((sb.y >> (8 * j)) & 255u) == base + (unsigned)ln) ? (short)0x3F80 : (short)0;
        a3c[0] = __builtin_amdgcn_mfma_f32_16x16x32_bf16(af.v, bfrg[kk][0], a3c[0], 0, 0, 0);
        a3c[1] = __builtin_amdgcn_mfma_f32_16x16x32_bf16(af.v, bfrg[kk][1], a3c[1], 0, 0, 0);
      }
#pragma unroll
      for (int ni = 0; ni < 2; ++ni)
#pragma unroll
        for (int r = 0; r < 4; ++r) {
          int run = (int)base + q * 4 + r;
          if (run < nruns) {
            int rw = runrowS[run];
            atomicAdd(&outAcc[(size_t)rw * 128 + (w * 32 + ni * 16 + ln)], a3c[ni][r]);
          }
        }
    }
  } else {
    float* ndl = (float*)A2s;   // reuse: [64][3]
    if (tid < 64) {
      float phi = redp[tid][0] + redp[tid][1];
      ndl[tid * 3 + 0] = ndS[(size_t)(tile * 64 + tid) * 3 + 0] * phi;
      ndl[tid * 3 + 1] = ndS[(size_t)(tile * 64 + tid) * 3 + 1] * phi;
      ndl[tid * 3 + 2] = ndS[(size_t)(tile * 64 + tid) * 3 + 2] * phi;
    }
    __syncthreads();
    if (is_start) {   // run-start walkers (tid<64 implied)
      int myrow = srow[tid];
      float s0 = 0.f, s1 = 0.f, s2 = 0.f;
      for (int j = tid; j < 64 && srow[j] == myrow; ++j) {
        s0 += ndl[j * 3 + 0];
        s1 += ndl[j * 3 + 1];
        s2 += ndl[j * 3 + 2];
      }
      atomicAdd(&outAcc[myrow * 3 + 0], s0);
      atomicAdd(&outAcc[myrow * 3 + 1], s1);
      atomicAdd(&outAcc[myrow * 3 + 2], s2);
    }
  }
}

// ---------------- node MLP GEMM (residual update, 128-node tiles, bf16) ----------------
__global__ __launch_bounds__(256) void k_node_gemm(
    short* Anode, const short* __restrict__ Wn1l, const short* __restrict__ Wn2l,
    const float* __restrict__ b1, const float* __restrict__ b2,
    const float* __restrict__ xres, float* __restrict__ xout) {
  __shared__ short A2s[4 * 4096];

  const int tid = threadIdx.x;
  const int lane = tid & 63;
  const int w = tid >> 6;
  const int ln = lane & 15, q = lane >> 4;
  const int wm = w >> 1, wn = w & 1;
  const int tile = blockIdx.x;

  size_t nbase[4];
  int wofs[4];
#pragma unroll
  for (int i = 0; i < 4; ++i) {
    int node = tile * 128 + wm * 64 + i * 16 + ln;
    nbase[i] = (size_t)(node < NN ? node : (NN - 1)) * 256;
    wofs[i] = wfrag_off(wn * 64 + i * 16 + ln, q);
  }

  f32x4 acc[4][4];
  const f32x4 zero4 = {0.f, 0.f, 0.f, 0.f};
#pragma unroll
  for (int mi = 0; mi < 4; ++mi)
#pragma unroll
    for (int ni = 0; ni < 4; ++ni) acc[mi][ni] = zero4;

#pragma unroll
  for (int kk = 0; kk < 8; ++kk) {
    bf16x8 af[4], bfr[4];
#pragma unroll
    for (int i = 0; i < 4; ++i) af[i] = *(const bf16x8*)(Anode + nbase[i] + kk * 32 + q * 8);
#pragma unroll
    for (int i = 0; i < 4; ++i) bfr[i] = *(const bf16x8*)(Wn1l + kk * 4096 + wofs[i]);
#pragma unroll
    for (int mi = 0; mi < 4; ++mi)
#pragma unroll
      for (int ni = 0; ni < 4; ++ni)
        acc[mi][ni] = __builtin_amdgcn_mfma_f32_16x16x32_bf16(af[mi], bfr[ni], acc[mi][ni], 0, 0, 0);
  }

  float b1v[4];
#pragma unroll
  for (int ni = 0; ni < 4; ++ni) b1v[ni] = b1[wn * 64 + ni * 16 + ln];
#pragma unroll
  for (int mi = 0; mi < 4; ++mi)
#pragma unroll
    for (int ni = 0; ni < 4; ++ni) {
      int chan = wn * 64 + ni * 16 + ln;
      int kkb = chan >> 5, c = (chan >> 3) & 3, jj = chan & 7;
#pragma unroll
      for (int r = 0; r < 4; ++r) {
        int m = wm * 64 + mi * 16 + q * 4 + r;
        float v = silu_f(acc[mi][ni][r] + b1v[ni]);
        A2s[kkb * 4096 + m * 32 + ((c ^ ((m >> 1) & 3)) * 8) + jj] = (short)f2bf(v);
      }
    }
  __syncthreads();

  f32x4 acc2[4][4];
#pragma unroll
  for (int mi = 0; mi < 4; ++mi)
#pragma unroll
    for (int ni = 0; ni < 4; ++ni) acc2[mi][ni] = zero4;
#pragma unroll
  for (int kk = 0; kk < 4; ++kk) {
    bf16x8 af[4], bfr[4];
#pragma unroll
    for (int i = 0; i < 4; ++i) af[i] = frag_ld(A2s + kk * 4096, wm * 64 + i * 16 + ln, q);
#pragma unroll
    for (int i = 0; i < 4; ++i) bfr[i] = *(const bf16x8*)(Wn2l + kk * 4096 + wofs[i]);
#pragma unroll
    for (int mi = 0; mi < 4; ++mi)
#pragma unroll
      for (int ni = 0; ni < 4; ++ni)
        acc2[mi][ni] = __builtin_amdgcn_mfma_f32_16x16x32_bf16(af[mi], bfr[ni], acc2[mi][ni], 0, 0, 0);
  }

  float b2v[4];
#pragma unroll
  for (int ni = 0; ni < 4; ++ni) b2v[ni] = b2[wn * 64 + ni * 16 + ln];
#pragma unroll
  for (int mi = 0; mi < 4; ++mi)
#pragma unroll
    for (int r = 0; r < 4; ++r) {
      int m = wm * 64 + mi * 16 + q * 4 + r;
      int node = tile * 128 + m;
      if (node < NN) {
#pragma unroll
        for (int ni = 0; ni < 4; ++ni) {
          int chan = wn * 64 + ni * 16 + ln;
          float v = acc2[mi][ni][r] + b2v[ni] + xres[(size_t)node * 128 + chan];
          xout[(size_t)node * 128 + chan] = v;
          Anode[(size_t)node * 256 + chan] = (short)f2bf(v);
        }
      }
    }
}

extern "C" void kernel_launch(void* const* d_in, const int* in_sizes, int n_in,
                              void* d_out, int out_size, void* d_ws, size_t ws_size,
                              hipStream_t stream) {
  const float* x    = (const float*)d_in[0];
  const float* pos  = (const float*)d_in[1];
  const float* mask = (const float*)d_in[2];
  const float* eattr= (const float*)d_in[3];
  const int*   ei   = (const int*)d_in[4];
  const float* We1  = (const float*)d_in[5];
  const float* be1  = (const float*)d_in[6];
  const float* We2  = (const float*)d_in[7];
  const float* be2  = (const float*)d_in[8];
  const float* Watt = (const float*)d_in[9];
  const float* batt = (const float*)d_in[10];
  const float* Wn1  = (const float*)d_in[11];
  const float* bn1  = (const float*)d_in[12];
  const float* Wn2  = (const float*)d_in[13];
  const float* bn2  = (const float*)d_in[14];
  const float* cW1  = (const float*)d_in[15];
  const float* cb1  = (const float*)d_in[16];
  const float* cW2  = (const float*)d_in[17];
  const float* cb2  = (const float*)d_in[18];
  const float* cW3  = (const float*)d_in[19];

  char* p = (char*)d_ws;
  auto carve = [&](size_t bytes) { char* r = p; p += (bytes + 511) & ~(size_t)511; return r; };
  short*   Anode = (short*)carve((size_t)NN * 256 * 2);
  uint8_t* XF8   = (uint8_t*)carve((size_t)NN * 128);
  uint8_t* eaF8  = (uint8_t*)carve((size_t)NE * 16 + 256);
  int*     rowS  = (int*)carve((size_t)NE * 4);
  int*     colS  = (int*)carve((size_t)NE * 4);
  float*   ndS   = (float*)carve((size_t)NE * 3 * 4);
  float*   agg   = (float*)carve((size_t)NN * 128 * 4);
  float*   xcur  = (float*)carve((size_t)NN * 128 * 4);
  float*   pagg  = (float*)carve((size_t)NN * 3 * 4);
  uint8_t* W1f8  = (uint8_t*)carve(3 * 36864);
  short*   W2sw  = (short*)carve(3 * 16384 * 2);
  short*   Wn1sw = (short*)carve(2 * 32768 * 2);
  short*   Wn2sw = (short*)carve(2 * 16384 * 2);
  int*     cnt   = (int*)carve((size_t)NN * 4);
  int*     offs  = (int*)carve((size_t)NN * 4);
  int*     bsum  = (int*)carve(256 * 4);
  int*     inv   = (int*)carve((size_t)NE * 4);

  float* xout_f = (float*)d_out;        // N*128
  float* pout_f = xout_f + NN * 128;    // N*3

  k_prep_weights<<<1008, 256, 0, stream>>>(We1, We2, Wn1, Wn2, cW1, cW2,
                                           W1f8, W2sw, Wn1sw, Wn2sw);
  k_init_xb<<<25000, 256, 0, stream>>>(x, Anode);
  k_xf8<<<6250, 256, 0, stream>>>(x, XF8);

  // build row-sorted edge permutation (CSR order) -> inv[e] = sorted slot
  hipMemsetAsync(cnt, 0, (size_t)NN * 4, stream);
  k_hist<<<3125, 256, 0, stream>>>(ei, cnt);
  k_scan_block<<<196, 256, 0, stream>>>(cnt, offs, bsum);
  k_scan_top<<<1, 256, 0, stream>>>(bsum);
  k_scan_add<<<196, 256, 0, stream>>>(offs, bsum);
  k_scatter<<<3125, 256, 0, stream>>>(ei, offs, inv);
  k_edge_pre<<<3125, 256, 0, stream>>>(pos, eattr, ei, inv, rowS, colS, eaF8, ndS);

  for (int l = 0; l < 2; ++l) {
    hipMemsetAsync(agg, 0, (size_t)NN * 128 * 4, stream);
    k_edge_gemm<0><<<12500, 256, 0, stream>>>(XF8, eaF8, rowS, colS,
        W1f8 + l * 36864, W2sw + l * 16384, be1 + l * 128, be2 + l * 128,
        Watt + l * 128, batt + l, (const float*)nullptr, agg);
    k_nodeprep<<<25000, 256, 0, stream>>>(agg, Anode);
    k_node_gemm<<<391, 256, 0, stream>>>(Anode,
        Wn1sw + l * 32768, Wn2sw + l * 16384, bn1 + l * 128, bn2 + l * 128,
        l == 0 ? x : xcur, l == 0 ? xcur : xout_f);
    k_xf8<<<6250, 256, 0, stream>>>(l == 0 ? xcur : xout_f, XF8);
  }
  hipMemsetAsync(pagg, 0, (size_t)NN * 3 * 4, stream);
  k_edge_gemm<1><<<12500, 256, 0, stream>>>(XF8, eaF8, rowS, colS,
      W1f8 + 2 * 36864, W2sw + 2 * 16384, cb1, cb2, cW3, (const float*)nullptr, ndS, pagg);
  k_pos_final<<<587, 256, 0, stream>>>(pos, mask, pagg, pout_f);
}